// Round 1
// baseline (4272.414 us; speedup 1.0000x reference)
//
#include <hip/hip_runtime.h>
#include <hip/hip_bf16.h>
#include <stdint.h>

// Problem constants
#define P 2048
#define V 50257
#define D 4096
#define CAP 128            // candidate slots per row
#define MARGIN 1.5e-3f     // ~60 sigma of bf16 dot error (~2.5e-5)

#define BM 128
#define BN 128
#define BK 32

using frag_ab = __attribute__((ext_vector_type(8))) short;  // 8 bf16 (4 VGPRs)
using frag_cd = __attribute__((ext_vector_type(4))) float;  // 4 fp32 acc

__device__ __forceinline__ unsigned short f2bf(float f) {
    __hip_bfloat16 h = __float2bfloat16(f);
    return *(unsigned short*)&h;
}

// monotone key: order of key == order of float (incl. negatives)
__device__ __forceinline__ uint32_t fkey(float f) {
    uint32_t u = __float_as_uint(f);
    return (u & 0x80000000u) ? ~u : (u | 0x80000000u);
}
__device__ __forceinline__ float key2f(uint32_t k) {
    uint32_t u = (k & 0x80000000u) ? (k ^ 0x80000000u) : ~k;
    return __uint_as_float(u);
}

// ---------------- Pass 0: normalize embeddings -> bf16, init state ----------
__global__ __launch_bounds__(256) void normalize_e(
        const float* __restrict__ E, unsigned short* __restrict__ Abf,
        unsigned long long* __restrict__ packmax, int* __restrict__ cnt) {
    const int p = blockIdx.x;
    const int t = threadIdx.x;
    const float* row = E + (size_t)p * D;

    float4 vals[4];
    float ss = 0.f;
#pragma unroll
    for (int c = 0; c < 4; c++) {
        vals[c] = ((const float4*)row)[c * 256 + t];
        ss += vals[c].x * vals[c].x + vals[c].y * vals[c].y
            + vals[c].z * vals[c].z + vals[c].w * vals[c].w;
    }
#pragma unroll
    for (int o = 1; o < 64; o <<= 1) ss += __shfl_xor(ss, o);
    __shared__ float wss[4];
    if ((t & 63) == 0) wss[t >> 6] = ss;
    __syncthreads();
    float tot = wss[0] + wss[1] + wss[2] + wss[3];
    float inv = 1.0f / fmaxf(sqrtf(tot), 1e-8f);

    unsigned short* dst = Abf + (size_t)p * D;
#pragma unroll
    for (int c = 0; c < 4; c++) {
        float4 v = vals[c];
        uint2 st;
        st.x = (uint32_t)f2bf(v.x * inv) | ((uint32_t)f2bf(v.y * inv) << 16);
        st.y = (uint32_t)f2bf(v.z * inv) | ((uint32_t)f2bf(v.w * inv) << 16);
        ((uint2*)dst)[c * 256 + t] = st;
    }
    if (t == 0) { packmax[p] = 0ull; cnt[p] = 0; }
}

// ---------------- Pass 1: bf16 MFMA GEMM + fused norms + argmax/candidates --
__global__ __launch_bounds__(256) void gemm_argmax(
        const unsigned short* __restrict__ Abf,   // [P][D] bf16 (normalized)
        const float* __restrict__ T,              // [V][D] fp32
        unsigned long long* __restrict__ packmax,
        int* __restrict__ cnt, int* __restrict__ cand) {
    __shared__ unsigned short As[BM * BK];  // 8 KB
    __shared__ unsigned short Bs[BN * BK];  // 8 KB
    __shared__ float invt[BN];

    const int t = threadIdx.x;
    const int m0 = blockIdx.x * BM;         // x fastest: 16 M-blocks share a B tile in L2
    const int v0 = blockIdx.y * BN;
    const int lane = t & 63;
    const int wm = (t >> 6) & 1, wn = (t >> 6) >> 1;
    const int l15 = lane & 15, lq = lane >> 4;
    const int r0 = t >> 2, q0 = t & 3;      // staging: 4 threads per tile-row

    frag_cd acc[4][4] = {};
    float ssq0 = 0.f, ssq1 = 0.f;           // table row sum-of-squares partials

    for (int k0 = 0; k0 < D; k0 += BK) {
        // global loads into registers (before barrier, lets them overlap)
        uint4 areg[2];
        float4 b0[2], b1[2];
#pragma unroll
        for (int pass = 0; pass < 2; pass++) {
            int row = pass * 64 + r0;
            areg[pass] = *(const uint4*)(Abf + (size_t)(m0 + row) * D + k0 + q0 * 8);
            int v = v0 + row;
            if (v < V) {
                const float* src = T + (size_t)v * D + k0 + q0 * 8;
                b0[pass] = *(const float4*)src;
                b1[pass] = *(const float4*)(src + 4);
            } else {
                b0[pass] = float4{0.f, 0.f, 0.f, 0.f};
                b1[pass] = float4{0.f, 0.f, 0.f, 0.f};
            }
        }
        __syncthreads();   // previous iteration's fragment reads done
#pragma unroll
        for (int pass = 0; pass < 2; pass++) {
            *(uint4*)&As[(size_t)(pass * 256 + t) * 8] = areg[pass];
            float4 x = b0[pass], y = b1[pass];
            float s = x.x * x.x + x.y * x.y + x.z * x.z + x.w * x.w
                    + y.x * y.x + y.y * y.y + y.z * y.z + y.w * y.w;
            if (pass == 0) ssq0 += s; else ssq1 += s;
            uint4 bv;
            bv.x = (uint32_t)f2bf(x.x) | ((uint32_t)f2bf(x.y) << 16);
            bv.y = (uint32_t)f2bf(x.z) | ((uint32_t)f2bf(x.w) << 16);
            bv.z = (uint32_t)f2bf(y.x) | ((uint32_t)f2bf(y.y) << 16);
            bv.w = (uint32_t)f2bf(y.z) | ((uint32_t)f2bf(y.w) << 16);
            *(uint4*)&Bs[(size_t)(pass * 256 + t) * 8] = bv;
        }
        __syncthreads();   // tiles visible

        frag_ab af[4], bf[4];
#pragma unroll
        for (int i = 0; i < 4; i++)
            af[i] = *(const frag_ab*)&As[(wm * 64 + i * 16 + l15) * BK + lq * 8];
#pragma unroll
        for (int j = 0; j < 4; j++)
            bf[j] = *(const frag_ab*)&Bs[(wn * 64 + j * 16 + l15) * BK + lq * 8];
#pragma unroll
        for (int i = 0; i < 4; i++)
#pragma unroll
            for (int j = 0; j < 4; j++)
                acc[i][j] = __builtin_amdgcn_mfma_f32_16x16x32_bf16(af[i], bf[j], acc[i][j], 0, 0, 0);
    }

    // table-row inverse norms (4 staging threads per row -> shfl combine)
    ssq0 += __shfl_xor(ssq0, 1); ssq0 += __shfl_xor(ssq0, 2);
    ssq1 += __shfl_xor(ssq1, 1); ssq1 += __shfl_xor(ssq1, 2);
    __syncthreads();
    if ((t & 3) == 0) {
        invt[r0]      = ssq0 > 0.f ? rsqrtf(ssq0) : 0.f;
        invt[64 + r0] = ssq1 > 0.f ? rsqrtf(ssq1) : 0.f;
    }
    __syncthreads();

    // epilogue: per embedding-row running max (packed) + candidate append
#pragma unroll
    for (int i = 0; i < 4; i++) {
#pragma unroll
        for (int r = 0; r < 4; r++) {
            const int p = m0 + wm * 64 + i * 16 + lq * 4 + r;  // C row = lq*4+reg
            float sc[4];
            int nidx[4];
            unsigned long long best = 0ull;
#pragma unroll
            for (int j = 0; j < 4; j++) {
                int nl = wn * 64 + j * 16 + l15;               // C col = lane&15
                int n = v0 + nl;
                float s = -2.0f;
                if (n < V) s = acc[i][j][r] * invt[nl];
                sc[j] = s; nidx[j] = n;
                if (n < V) {
                    unsigned long long pk =
                        ((unsigned long long)fkey(s) << 32) |
                        (unsigned long long)(0xFFFFFFFFu - (uint32_t)n);
                    if (pk > best) best = pk;
                }
            }
            // 16-lane (n-direction) max reduce
#pragma unroll
            for (int o = 1; o < 16; o <<= 1) {
                unsigned long long other = __shfl_xor(best, o);
                if (other > best) best = other;
            }
            unsigned long long oldpk = 0ull;
            if (l15 == 0) oldpk = atomicMax(packmax + p, best);
            oldpk = __shfl(oldpk, lane & 48);   // broadcast from group leader
            unsigned long long merged = best > oldpk ? best : oldpk;
            float thr = key2f((uint32_t)(merged >> 32)) - MARGIN;
#pragma unroll
            for (int j = 0; j < 4; j++) {
                if (nidx[j] < V && sc[j] >= thr) {
                    int slot = atomicAdd(cnt + p, 1);
                    if (slot < CAP) cand[p * CAP + slot] = nidx[j];
                }
            }
        }
    }
}

// ---------------- Pass 2: exact fp64 rescore of candidates ------------------
__global__ __launch_bounds__(256) void rescore(
        const float* __restrict__ E, const float* __restrict__ T,
        const unsigned long long* __restrict__ packmax,
        const int* __restrict__ cnt, const int* __restrict__ cand,
        int* __restrict__ out) {
    __shared__ double rd[4], rs[4];
    const int p = blockIdx.x;
    const int t = threadIdx.x;
    const float* e = E + (size_t)p * D;

    const int c = cnt[p];
    const bool overflow = c > CAP;
    const int ncand = overflow ? 0 : c;

    unsigned long long pk = packmax[p];
    const int pv = (int)(0xFFFFFFFFu - (uint32_t)(pk & 0xFFFFFFFFull));

    double best_s = -3.0;
    int best_v = 0x7FFFFFFF;

    auto eval = [&](int v) -> double {
        const float* tr = T + (size_t)v * D;
        double dot = 0.0, ss = 0.0;
        for (int i = t; i < D; i += 256) {
            double ev = e[i], tv = tr[i];
            dot += ev * tv;
            ss  += tv * tv;
        }
#pragma unroll
        for (int o = 1; o < 64; o <<= 1) {
            dot += __shfl_xor(dot, o);
            ss  += __shfl_xor(ss, o);
        }
        if ((t & 63) == 0) { rd[t >> 6] = dot; rs[t >> 6] = ss; }
        __syncthreads();
        double d = rd[0] + rd[1] + rd[2] + rd[3];
        double s = rs[0] + rs[1] + rs[2] + rs[3];
        __syncthreads();
        return d / fmax(sqrt(s), 1e-8);
    };
    auto consider = [&](int v, double s) {
        if (s > best_s || (s == best_s && v < best_v)) { best_s = s; best_v = v; }
    };

    if (!overflow) {
        consider(pv, eval(pv));
        for (int ci = 0; ci < ncand; ci++) {
            int v = cand[p * CAP + ci];
            if (v == pv) continue;
            consider(v, eval(v));
        }
    } else {
        // statistical never-case safety net: exact full scan
        for (int v = 0; v < V; v++) consider(v, eval(v));
    }
    if (t == 0) out[p] = best_v;
}

// ---------------- Launch ----------------------------------------------------
extern "C" void kernel_launch(void* const* d_in, const int* in_sizes, int n_in,
                              void* d_out, int out_size, void* d_ws, size_t ws_size,
                              hipStream_t stream) {
    const float* E = (const float*)d_in[0];   // [2048,4096] fp32
    const float* T = (const float*)d_in[1];   // [50257,4096] fp32
    int* out = (int*)d_out;                   // [2048] int32 ids

    // ws layout (all 16B-aligned):
    //  0                : Abf      2048*4096*2 = 16,777,216
    //  16,777,216       : packmax  2048*8      = 16,384
    //  16,793,600       : cnt      2048*4      = 8,192
    //  16,801,792       : cand     2048*128*4  = 1,048,576   (total ~17.85 MB)
    char* ws = (char*)d_ws;
    unsigned short* Abf = (unsigned short*)ws;
    unsigned long long* packmax = (unsigned long long*)(ws + 16777216);
    int* cnt  = (int*)(ws + 16793600);
    int* cand = (int*)(ws + 16801792);

    normalize_e<<<P, 256, 0, stream>>>(E, Abf, packmax, cnt);
    dim3 g1(P / BM, (V + BN - 1) / BN);   // 16 x 393, x fastest for B-tile L2 reuse
    gemm_argmax<<<g1, 256, 0, stream>>>(Abf, T, packmax, cnt, cand);
    rescore<<<P, 256, 0, stream>>>(E, T, packmax, cnt, cand, out);
}

// Round 2
// 2455.114 us; speedup vs baseline: 1.7402x; 1.7402x over previous
//
#include <hip/hip_runtime.h>
#include <hip/hip_bf16.h>
#include <stdint.h>

// Problem constants
#define P 2048
#define V 50257
#define D 4096
#define CAP 128            // candidate slots per row
#define MARGIN 1.5e-3f     // ~35 sigma of bf16 dot error (~4e-5 std)

#define BM 128
#define BN 128
#define BK 32

using frag_ab = __attribute__((ext_vector_type(8))) short;  // 8 bf16 (4 VGPRs)
using frag_cd = __attribute__((ext_vector_type(4))) float;  // 4 fp32 acc

__device__ __forceinline__ unsigned short f2bf(float f) {
    __hip_bfloat16 h = __float2bfloat16(f);
    return *(unsigned short*)&h;
}

// monotone key: order of key == order of float (incl. negatives)
__device__ __forceinline__ uint32_t fkey(float f) {
    uint32_t u = __float_as_uint(f);
    return (u & 0x80000000u) ? ~u : (u | 0x80000000u);
}
__device__ __forceinline__ float key2f(uint32_t k) {
    uint32_t u = (k & 0x80000000u) ? (k ^ 0x80000000u) : ~k;
    return __uint_as_float(u);
}

#define GLD_LDS16(g, l) __builtin_amdgcn_global_load_lds(                      \
    (const __attribute__((address_space(1))) void*)(g),                        \
    (__attribute__((address_space(3))) void*)(l), 16, 0, 0)

// ---------------- normalize embeddings -> bf16, init state ------------------
__global__ __launch_bounds__(256) void normalize_e(
        const float* __restrict__ E, unsigned short* __restrict__ Abf,
        unsigned long long* __restrict__ packmax, int* __restrict__ cnt) {
    const int p = blockIdx.x;
    const int t = threadIdx.x;
    const float* row = E + (size_t)p * D;

    float4 vals[4];
    float ss = 0.f;
#pragma unroll
    for (int c = 0; c < 4; c++) {
        vals[c] = ((const float4*)row)[c * 256 + t];
        ss += vals[c].x * vals[c].x + vals[c].y * vals[c].y
            + vals[c].z * vals[c].z + vals[c].w * vals[c].w;
    }
#pragma unroll
    for (int o = 1; o < 64; o <<= 1) ss += __shfl_xor(ss, o);
    __shared__ float wss[4];
    if ((t & 63) == 0) wss[t >> 6] = ss;
    __syncthreads();
    float tot = wss[0] + wss[1] + wss[2] + wss[3];
    float inv = 1.0f / fmaxf(sqrtf(tot), 1e-8f);

    unsigned short* dst = Abf + (size_t)p * D;
#pragma unroll
    for (int c = 0; c < 4; c++) {
        float4 v = vals[c];
        uint2 st;
        st.x = (uint32_t)f2bf(v.x * inv) | ((uint32_t)f2bf(v.y * inv) << 16);
        st.y = (uint32_t)f2bf(v.z * inv) | ((uint32_t)f2bf(v.w * inv) << 16);
        ((uint2*)dst)[c * 256 + t] = st;
    }
    if (t == 0) { packmax[p] = 0ull; cnt[p] = 0; }
}

// ---------------- normalize table row -> bf16 (fast path only) --------------
__global__ __launch_bounds__(256) void normalize_t(
        const float* __restrict__ T, unsigned short* __restrict__ Tbf) {
    const int v = blockIdx.x;
    const int t = threadIdx.x;
    const float* row = T + (size_t)v * D;

    float4 vals[4];
    float ss = 0.f;
#pragma unroll
    for (int c = 0; c < 4; c++) {
        vals[c] = ((const float4*)row)[c * 256 + t];
        ss += vals[c].x * vals[c].x + vals[c].y * vals[c].y
            + vals[c].z * vals[c].z + vals[c].w * vals[c].w;
    }
#pragma unroll
    for (int o = 1; o < 64; o <<= 1) ss += __shfl_xor(ss, o);
    __shared__ float wss[4];
    if ((t & 63) == 0) wss[t >> 6] = ss;
    __syncthreads();
    float tot = wss[0] + wss[1] + wss[2] + wss[3];
    float inv = 1.0f / fmaxf(sqrtf(tot), 1e-8f);

    unsigned short* dst = Tbf + (size_t)v * D;
#pragma unroll
    for (int c = 0; c < 4; c++) {
        float4 x = vals[c];
        uint2 st;
        st.x = (uint32_t)f2bf(x.x * inv) | ((uint32_t)f2bf(x.y * inv) << 16);
        st.y = (uint32_t)f2bf(x.z * inv) | ((uint32_t)f2bf(x.w * inv) << 16);
        ((uint2*)dst)[c * 256 + t] = st;
    }
}

// ---------------- FAST PATH: bf16 x bf16 MFMA GEMM + argmax epilogue --------
// m97 structure: 128x128 tile, BK=32, global_load_lds width=16, 2-barrier loop
__global__ __launch_bounds__(256) void gemm_bf16_argmax(
        const unsigned short* __restrict__ Abf,   // [P][D] bf16 (normalized)
        const unsigned short* __restrict__ Tbf,   // [V][D] bf16 (normalized)
        unsigned long long* __restrict__ packmax,
        int* __restrict__ cnt, int* __restrict__ cand) {
    __shared__ unsigned short As[BM * BK];  // 8 KB, row-major [row][32]
    __shared__ unsigned short Bs[BN * BK];  // 8 KB

    const int t = threadIdx.x;
    const int m0 = blockIdx.x * BM;   // x fastest: 16 M-blocks share a B tile
    const int v0 = blockIdx.y * BN;
    const int lane = t & 63;
    const int w = t >> 6;
    const int wm = w & 1, wn = w >> 1;
    const int l15 = lane & 15, lq = lane >> 4;

    // staging: wave w owns chunks {w, w+4}; chunk c = rows 16c..16c+15.
    // lane i -> row 16c + i/4, element col (i&3)*8; LDS dest = base + lane*16B
    const int srow = lane >> 2;
    const int scol = (lane & 3) * 8;
    const unsigned short* gA0 = Abf + (size_t)(m0 + w * 16 + srow) * D + scol;
    const unsigned short* gA1 = gA0 + (size_t)64 * D;
    int rb0 = v0 + w * 16 + srow;      if (rb0 > V - 1) rb0 = V - 1;
    int rb1 = v0 + (w + 4) * 16 + srow; if (rb1 > V - 1) rb1 = V - 1;
    const unsigned short* gB0 = Tbf + (size_t)rb0 * D + scol;
    const unsigned short* gB1 = Tbf + (size_t)rb1 * D + scol;
    unsigned short* lA0 = &As[(size_t)w * 512];
    unsigned short* lA1 = &As[(size_t)(w + 4) * 512];
    unsigned short* lB0 = &Bs[(size_t)w * 512];
    unsigned short* lB1 = &Bs[(size_t)(w + 4) * 512];

    frag_cd acc[4][4] = {};

    for (int k0 = 0; k0 < D; k0 += BK) {
        __syncthreads();   // previous iteration's fragment reads done
        GLD_LDS16(gA0 + k0, lA0);
        GLD_LDS16(gA1 + k0, lA1);
        GLD_LDS16(gB0 + k0, lB0);
        GLD_LDS16(gB1 + k0, lB1);
        __syncthreads();   // compiler drains vmcnt(0) before s_barrier

        frag_ab af[4], bf[4];
#pragma unroll
        for (int i = 0; i < 4; i++)
            af[i] = *(const frag_ab*)&As[(wm * 64 + i * 16 + l15) * BK + lq * 8];
#pragma unroll
        for (int j = 0; j < 4; j++)
            bf[j] = *(const frag_ab*)&Bs[(wn * 64 + j * 16 + l15) * BK + lq * 8];
#pragma unroll
        for (int i = 0; i < 4; i++)
#pragma unroll
            for (int j = 0; j < 4; j++)
                acc[i][j] = __builtin_amdgcn_mfma_f32_16x16x32_bf16(af[i], bf[j], acc[i][j], 0, 0, 0);
    }

    // epilogue: per embedding-row running max (packed) + candidate append
#pragma unroll
    for (int i = 0; i < 4; i++) {
#pragma unroll
        for (int r = 0; r < 4; r++) {
            const int p = m0 + wm * 64 + i * 16 + lq * 4 + r;  // C row = lq*4+reg
            float sc[4];
            int nidx[4];
            unsigned long long best = 0ull;
#pragma unroll
            for (int j = 0; j < 4; j++) {
                int nl = wn * 64 + j * 16 + l15;               // C col = lane&15
                int n = v0 + nl;
                float s = -2.0f;
                if (n < V) s = acc[i][j][r];
                sc[j] = s; nidx[j] = n;
                if (n < V) {
                    unsigned long long pk =
                        ((unsigned long long)fkey(s) << 32) |
                        (unsigned long long)(0xFFFFFFFFu - (uint32_t)n);
                    if (pk > best) best = pk;
                }
            }
#pragma unroll
            for (int o = 1; o < 16; o <<= 1) {
                unsigned long long other = __shfl_xor(best, o);
                if (other > best) best = other;
            }
            unsigned long long oldpk = 0ull;
            if (l15 == 0) oldpk = atomicMax(packmax + p, best);
            oldpk = __shfl(oldpk, lane & 48);   // broadcast from group leader
            unsigned long long merged = best > oldpk ? best : oldpk;
            float thr = key2f((uint32_t)(merged >> 32)) - MARGIN;
#pragma unroll
            for (int j = 0; j < 4; j++) {
                if (nidx[j] < V && sc[j] >= thr) {
                    int slot = atomicAdd(cnt + p, 1);
                    if (slot < CAP) cand[p * CAP + slot] = nidx[j];
                }
            }
        }
    }
}

// ---------------- SLOW PATH (ws too small): fp32-table on-the-fly GEMM ------
__global__ __launch_bounds__(256) void gemm_argmax(
        const unsigned short* __restrict__ Abf,   // [P][D] bf16 (normalized)
        const float* __restrict__ T,              // [V][D] fp32
        unsigned long long* __restrict__ packmax,
        int* __restrict__ cnt, int* __restrict__ cand) {
    __shared__ unsigned short As[BM * BK];
    __shared__ unsigned short Bs[BN * BK];
    __shared__ float invt[BN];

    const int t = threadIdx.x;
    const int m0 = blockIdx.x * BM;
    const int v0 = blockIdx.y * BN;
    const int lane = t & 63;
    const int wm = (t >> 6) & 1, wn = (t >> 6) >> 1;
    const int l15 = lane & 15, lq = lane >> 4;
    const int r0 = t >> 2, q0 = t & 3;

    frag_cd acc[4][4] = {};
    float ssq0 = 0.f, ssq1 = 0.f;

    for (int k0 = 0; k0 < D; k0 += BK) {
        uint4 areg[2];
        float4 b0[2], b1[2];
#pragma unroll
        for (int pass = 0; pass < 2; pass++) {
            int row = pass * 64 + r0;
            areg[pass] = *(const uint4*)(Abf + (size_t)(m0 + row) * D + k0 + q0 * 8);
            int v = v0 + row;
            if (v < V) {
                const float* src = T + (size_t)v * D + k0 + q0 * 8;
                b0[pass] = *(const float4*)src;
                b1[pass] = *(const float4*)(src + 4);
            } else {
                b0[pass] = float4{0.f, 0.f, 0.f, 0.f};
                b1[pass] = float4{0.f, 0.f, 0.f, 0.f};
            }
        }
        __syncthreads();
#pragma unroll
        for (int pass = 0; pass < 2; pass++) {
            *(uint4*)&As[(size_t)(pass * 256 + t) * 8] = areg[pass];
            float4 x = b0[pass], y = b1[pass];
            float s = x.x * x.x + x.y * x.y + x.z * x.z + x.w * x.w
                    + y.x * y.x + y.y * y.y + y.z * y.z + y.w * y.w;
            if (pass == 0) ssq0 += s; else ssq1 += s;
            uint4 bv;
            bv.x = (uint32_t)f2bf(x.x) | ((uint32_t)f2bf(x.y) << 16);
            bv.y = (uint32_t)f2bf(x.z) | ((uint32_t)f2bf(x.w) << 16);
            bv.z = (uint32_t)f2bf(y.x) | ((uint32_t)f2bf(y.y) << 16);
            bv.w = (uint32_t)f2bf(y.z) | ((uint32_t)f2bf(y.w) << 16);
            *(uint4*)&Bs[(size_t)(pass * 256 + t) * 8] = bv;
        }
        __syncthreads();

        frag_ab af[4], bf[4];
#pragma unroll
        for (int i = 0; i < 4; i++)
            af[i] = *(const frag_ab*)&As[(wm * 64 + i * 16 + l15) * BK + lq * 8];
#pragma unroll
        for (int j = 0; j < 4; j++)
            bf[j] = *(const frag_ab*)&Bs[(wn * 64 + j * 16 + l15) * BK + lq * 8];
#pragma unroll
        for (int i = 0; i < 4; i++)
#pragma unroll
            for (int j = 0; j < 4; j++)
                acc[i][j] = __builtin_amdgcn_mfma_f32_16x16x32_bf16(af[i], bf[j], acc[i][j], 0, 0, 0);
    }

    ssq0 += __shfl_xor(ssq0, 1); ssq0 += __shfl_xor(ssq0, 2);
    ssq1 += __shfl_xor(ssq1, 1); ssq1 += __shfl_xor(ssq1, 2);
    __syncthreads();
    if ((t & 3) == 0) {
        invt[r0]      = ssq0 > 0.f ? rsqrtf(ssq0) : 0.f;
        invt[64 + r0] = ssq1 > 0.f ? rsqrtf(ssq1) : 0.f;
    }
    __syncthreads();

#pragma unroll
    for (int i = 0; i < 4; i++) {
#pragma unroll
        for (int r = 0; r < 4; r++) {
            const int p = m0 + wm * 64 + i * 16 + lq * 4 + r;
            float sc[4];
            int nidx[4];
            unsigned long long best = 0ull;
#pragma unroll
            for (int j = 0; j < 4; j++) {
                int nl = wn * 64 + j * 16 + l15;
                int n = v0 + nl;
                float s = -2.0f;
                if (n < V) s = acc[i][j][r] * invt[nl];
                sc[j] = s; nidx[j] = n;
                if (n < V) {
                    unsigned long long pk =
                        ((unsigned long long)fkey(s) << 32) |
                        (unsigned long long)(0xFFFFFFFFu - (uint32_t)n);
                    if (pk > best) best = pk;
                }
            }
#pragma unroll
            for (int o = 1; o < 16; o <<= 1) {
                unsigned long long other = __shfl_xor(best, o);
                if (other > best) best = other;
            }
            unsigned long long oldpk = 0ull;
            if (l15 == 0) oldpk = atomicMax(packmax + p, best);
            oldpk = __shfl(oldpk, lane & 48);
            unsigned long long merged = best > oldpk ? best : oldpk;
            float thr = key2f((uint32_t)(merged >> 32)) - MARGIN;
#pragma unroll
            for (int j = 0; j < 4; j++) {
                if (nidx[j] < V && sc[j] >= thr) {
                    int slot = atomicAdd(cnt + p, 1);
                    if (slot < CAP) cand[p * CAP + slot] = nidx[j];
                }
            }
        }
    }
}

// ---------------- exact fp64 rescore of candidates (wave-parallel) ----------
__global__ __launch_bounds__(256) void rescore(
        const float* __restrict__ E, const float* __restrict__ T,
        const unsigned long long* __restrict__ packmax,
        const int* __restrict__ cnt, const int* __restrict__ cand,
        int* __restrict__ out) {
    const int p = blockIdx.x;
    const int t = threadIdx.x;
    const int w = t >> 6, lane = t & 63;
    const float* e = E + (size_t)p * D;

    const int c = cnt[p];
    const bool overflow = c > CAP;
    const int ncand = overflow ? 0 : c;

    unsigned long long pk = packmax[p];
    const int pv = (int)(0xFFFFFFFFu - (uint32_t)(pk & 0xFFFFFFFFull));

    double best_s = -3.0;
    int best_v = 0x7FFFFFFF;

    auto evalw = [&](int v) -> double {   // whole-wave fp64 cosine
        const float* tr = T + (size_t)v * D;
        double dot = 0.0, ss = 0.0;
        for (int i = lane; i < D; i += 64) {
            double ev = e[i], tv = tr[i];
            dot += ev * tv;
            ss  += tv * tv;
        }
#pragma unroll
        for (int o = 1; o < 64; o <<= 1) {
            dot += __shfl_xor(dot, o);
            ss  += __shfl_xor(ss, o);
        }
        return dot / fmax(sqrt(ss), 1e-8);
    };
    auto consider = [&](int v, double s) {
        if (s > best_s || (s == best_s && v < best_v)) { best_s = s; best_v = v; }
    };

    if (!overflow) {
        const int total = ncand + 1;
        for (int idx = w; idx < total; idx += 4) {
            int v = (idx == 0) ? pv : cand[p * CAP + idx - 1];
            consider(v, evalw(v));
        }
    } else {
        // statistical never-case safety net: exact full scan
        for (int v = w; v < V; v += 4) consider(v, evalw(v));
    }

    __shared__ double bs[4];
    __shared__ int bv[4];
    if (lane == 0) { bs[w] = best_s; bv[w] = best_v; }
    __syncthreads();
    if (t == 0) {
        double s = bs[0]; int v = bv[0];
#pragma unroll
        for (int i = 1; i < 4; i++)
            if (bs[i] > s || (bs[i] == s && bv[i] < v)) { s = bs[i]; v = bv[i]; }
        out[p] = v;
    }
}

// ---------------- Launch ----------------------------------------------------
extern "C" void kernel_launch(void* const* d_in, const int* in_sizes, int n_in,
                              void* d_out, int out_size, void* d_ws, size_t ws_size,
                              hipStream_t stream) {
    const float* E = (const float*)d_in[0];   // [2048,4096] fp32
    const float* T = (const float*)d_in[1];   // [50257,4096] fp32
    int* out = (int*)d_out;                   // [2048] int32 ids

    char* ws = (char*)d_ws;

    // fast-path ws layout:
    //  0           : Tbf      50257*4096*2 = 411,705,344
    //  411,705,344 : Abf      2048*4096*2  =  16,777,216
    //  428,482,560 : packmax  2048*8       =      16,384
    //  428,498,944 : cnt      2048*4       =       8,192
    //  428,507,136 : cand     2048*128*4   =   1,048,576
    //  total: 429,555,712
    const size_t FAST_WS = 429555712ull;

    if (ws_size >= FAST_WS) {
        unsigned short* Tbf = (unsigned short*)ws;
        unsigned short* Abf = (unsigned short*)(ws + 411705344ull);
        unsigned long long* packmax = (unsigned long long*)(ws + 428482560ull);
        int* cnt  = (int*)(ws + 428498944ull);
        int* cand = (int*)(ws + 428507136ull);

        normalize_e<<<P, 256, 0, stream>>>(E, Abf, packmax, cnt);
        normalize_t<<<V, 256, 0, stream>>>(T, Tbf);
        dim3 g1(P / BM, (V + BN - 1) / BN);   // 16 x 393, x fastest
        gemm_bf16_argmax<<<g1, 256, 0, stream>>>(Abf, Tbf, packmax, cnt, cand);
        rescore<<<P, 256, 0, stream>>>(E, T, packmax, cnt, cand, out);
    } else {
        // slow path (ws >= ~18 MB): on-the-fly fp32 table conversion
        unsigned short* Abf = (unsigned short*)ws;
        unsigned long long* packmax = (unsigned long long*)(ws + 16777216);
        int* cnt  = (int*)(ws + 16793600);
        int* cand = (int*)(ws + 16801792);

        normalize_e<<<P, 256, 0, stream>>>(E, Abf, packmax, cnt);
        dim3 g1(P / BM, (V + BN - 1) / BN);
        gemm_argmax<<<g1, 256, 0, stream>>>(Abf, T, packmax, cnt, cand);
        rescore<<<P, 256, 0, stream>>>(E, T, packmax, cnt, cand, out);
    }
}